// Round 3
// baseline (743.047 us; speedup 1.0000x reference)
//
#include <hip/hip_runtime.h>

#define N_NODES 100000
#define N_EDGES 3200000
#define SCAN_CHUNK 4096   // 256 threads x 16 elems
#define SCAN_BLOCKS 25    // ceil(100000 / 4096)

// ---------------------------------------------------------------------------
// Kernel A: feat = node_feat @ Wfc.T  (N x 64), el/er = sum(feat*attn, -1)
// LDS layout T2[k4][j][kk] so lane j reads one float4 (ds_read_b128) per 4 k.
// ---------------------------------------------------------------------------
__global__ __launch_bounds__(256) void node_proj(
    const float* __restrict__ node_feat,
    const float* __restrict__ Wfc,
    const float* __restrict__ attn_l,
    const float* __restrict__ attn_r,
    float* __restrict__ feat,
    float* __restrict__ el,
    float* __restrict__ er)
{
    __shared__ float T2[32 * 64 * 4];   // 32 KiB: T2[(k4*64 + j)*4 + kk] = Wfc[j*128 + k4*4+kk]
    const int tid = threadIdx.x;
    for (int i = tid; i < 64 * 128; i += 256) {
        int j = i >> 7, k = i & 127;
        T2[((k >> 2) * 64 + j) * 4 + (k & 3)] = Wfc[i];
    }
    __syncthreads();

    const int lane = tid & 63;
    const float al = attn_l[lane];
    const float ar = attn_r[lane];
    const int gw = blockIdx.x * 4 + (tid >> 6);
    const int nw = gridDim.x * 4;
    const float4* __restrict__ T2v = (const float4*)T2;

    for (int g = gw; g * 4 < N_NODES; g += nw) {
        const int n0 = g * 4;
        const float4* __restrict__ x0 = (const float4*)(node_feat + (size_t)(n0 + 0) * 128);
        const float4* __restrict__ x1 = (const float4*)(node_feat + (size_t)(n0 + 1) * 128);
        const float4* __restrict__ x2 = (const float4*)(node_feat + (size_t)(n0 + 2) * 128);
        const float4* __restrict__ x3 = (const float4*)(node_feat + (size_t)(n0 + 3) * 128);

        float acc0 = 0.f, acc1 = 0.f, acc2 = 0.f, acc3 = 0.f;
        #pragma unroll 8
        for (int k4 = 0; k4 < 32; ++k4) {
            const float4 v0 = x0[k4], v1 = x1[k4], v2 = x2[k4], v3 = x3[k4];
            const float4 w = T2v[k4 * 64 + lane];
            acc0 = fmaf(v0.x, w.x, acc0); acc0 = fmaf(v0.y, w.y, acc0);
            acc0 = fmaf(v0.z, w.z, acc0); acc0 = fmaf(v0.w, w.w, acc0);
            acc1 = fmaf(v1.x, w.x, acc1); acc1 = fmaf(v1.y, w.y, acc1);
            acc1 = fmaf(v1.z, w.z, acc1); acc1 = fmaf(v1.w, w.w, acc1);
            acc2 = fmaf(v2.x, w.x, acc2); acc2 = fmaf(v2.y, w.y, acc2);
            acc2 = fmaf(v2.z, w.z, acc2); acc2 = fmaf(v2.w, w.w, acc2);
            acc3 = fmaf(v3.x, w.x, acc3); acc3 = fmaf(v3.y, w.y, acc3);
            acc3 = fmaf(v3.z, w.z, acc3); acc3 = fmaf(v3.w, w.w, acc3);
        }

        feat[(size_t)(n0 + 0) * 64 + lane] = acc0;
        feat[(size_t)(n0 + 1) * 64 + lane] = acc1;
        feat[(size_t)(n0 + 2) * 64 + lane] = acc2;
        feat[(size_t)(n0 + 3) * 64 + lane] = acc3;

        const float accs[4] = {acc0, acc1, acc2, acc3};
        #pragma unroll
        for (int i = 0; i < 4; ++i) {
            float vl = accs[i] * al;
            float vr = accs[i] * ar;
            #pragma unroll
            for (int off = 8; off >= 1; off >>= 1) {
                vl += __shfl_xor(vl, off);
                vr += __shfl_xor(vr, off);
            }
            if ((lane & 15) == 0) {
                el[(size_t)(n0 + i) * 4 + (lane >> 4)] = vl;
                er[(size_t)(n0 + i) * 4 + (lane >> 4)] = vr;
            }
        }
    }
}

// ---------------------------------------------------------------------------
// CSR build: histogram -> scan -> scatter (single packed 8B payload per edge)
// ---------------------------------------------------------------------------
__global__ __launch_bounds__(256) void hist(const int* __restrict__ dst,
                                            int* __restrict__ counts)
{
    const int e = blockIdx.x * 256 + threadIdx.x;
    if (e < N_EDGES) atomicAdd(&counts[dst[e]], 1);
}

__global__ __launch_bounds__(256) void scan1(const int* __restrict__ counts,
                                             int* __restrict__ offsets,
                                             int* __restrict__ blockSums)
{
    __shared__ int lds[256];
    const int b = blockIdx.x, t = threadIdx.x;
    const int base = b * SCAN_CHUNK + t * 16;
    int v[16];
    int sum = 0;
    #pragma unroll
    for (int i = 0; i < 16; ++i) {
        int idx = base + i;
        v[i] = (idx < N_NODES) ? counts[idx] : 0;
        sum += v[i];
    }
    lds[t] = sum;
    __syncthreads();
    int x = sum;
    for (int off = 1; off < 256; off <<= 1) {
        int y = (t >= off) ? lds[t - off] : 0;
        __syncthreads();
        x += y;
        lds[t] = x;
        __syncthreads();
    }
    if (t == 255) blockSums[b] = x;
    int run = x - sum;   // exclusive
    #pragma unroll
    for (int i = 0; i < 16; ++i) {
        int idx = base + i;
        if (idx < N_NODES) offsets[idx] = run;
        run += v[i];
    }
}

__global__ void scan2(int* __restrict__ blockSums, int nb)
{
    if (threadIdx.x == 0 && blockIdx.x == 0) {
        int acc = 0;
        for (int i = 0; i < nb; ++i) { int v = blockSums[i]; blockSums[i] = acc; acc += v; }
    }
}

__global__ __launch_bounds__(256) void scan3(int* __restrict__ offsets,
                                             int* __restrict__ cursor,
                                             const int* __restrict__ blockSums)
{
    const int idx = blockIdx.x * 256 + threadIdx.x;
    if (idx < N_NODES) {
        int o = offsets[idx] + blockSums[idx >> 12];   // 4096 = 1<<12
        offsets[idx] = o;
        cursor[idx] = o;
    }
}

__global__ __launch_bounds__(256) void scatter(const int* __restrict__ src,
                                               const int* __restrict__ dst,
                                               int* __restrict__ cursor,
                                               unsigned long long* __restrict__ sedge)
{
    const int e = blockIdx.x * 256 + threadIdx.x;
    if (e >= N_EDGES) return;
    const int d = dst[e];
    const int pos = atomicAdd(&cursor[d], 1);
    sedge[pos] = ((unsigned long long)(unsigned)e << 32) | (unsigned)src[e];
}

// ---------------------------------------------------------------------------
// Aggregation: one wave per dst node. Lane j -> (c = j>>4, f = j&15).
// rst[dst] = (sum_e ee * feat[src]) / (sum_e ee).  No atomics, single store.
// ---------------------------------------------------------------------------
__global__ __launch_bounds__(256) void aggregate(
    const float* __restrict__ edge_feat,
    const float* __restrict__ We,
    const float* __restrict__ el,
    const float* __restrict__ er,
    const int* __restrict__ offsets,
    const int* __restrict__ counts,
    const unsigned long long* __restrict__ sedge,
    const float* __restrict__ feat,
    float* __restrict__ rst)
{
    const int node = (int)((blockIdx.x * 256 + threadIdx.x) >> 6);
    const int lane = threadIdx.x & 63;
    if (node >= N_NODES) return;
    const int c = lane >> 4;

    const float w0 = We[c * 4 + 0], w1 = We[c * 4 + 1];
    const float w2 = We[c * 4 + 2], w3 = We[c * 4 + 3];
    const float rc = er[(size_t)node * 4 + c];
    const int start = offsets[node];
    const int deg = counts[node];

    float acc = 0.f, ssum = 0.f;
    for (int base = 0; base < deg; base += 64) {
        const int n = min(64, deg - base);
        int si_l = 0, eid_l = 0;
        if (lane < n) {
            const unsigned long long p = sedge[start + base + lane];
            si_l  = (int)(unsigned)(p & 0xffffffffull);
            eid_l = (int)(unsigned)(p >> 32);
        }
        for (int i = 0; i < n; ++i) {
            const int si  = __shfl(si_l, i);
            const int eid = __shfl(eid_l, i);
            const float4 ef = ((const float4*)edge_feat)[eid];
            const float lc = el[(size_t)si * 4 + c];
            float t = lc + rc;
            t = t > 0.f ? t : 0.2f * t;
            const float ee = __expf(t * (w0 * ef.x + w1 * ef.y + w2 * ef.z + w3 * ef.w));
            const float fv = feat[(size_t)si * 64 + lane];
            acc = fmaf(ee, fv, acc);
            ssum += ee;
        }
    }
    rst[(size_t)node * 64 + lane] = (deg > 0) ? acc / ssum : 0.f;
}

// ---------------------------------------------------------------------------
extern "C" void kernel_launch(void* const* d_in, const int* in_sizes, int n_in,
                              void* d_out, int out_size, void* d_ws, size_t ws_size,
                              hipStream_t stream)
{
    const float* node_feat = (const float*)d_in[0];
    const float* edge_feat = (const float*)d_in[1];
    const int*   src       = (const int*)d_in[2];
    const int*   dst       = (const int*)d_in[3];
    const float* Wfc       = (const float*)d_in[4];
    const float* We        = (const float*)d_in[5];
    const float* attn_l    = (const float*)d_in[6];
    const float* attn_r    = (const float*)d_in[7];
    float* rst = (float*)d_out;

    char* ws = (char*)d_ws;
    float* feat      = (float*)(ws);                  // 25,600,000 B
    float* el        = (float*)(ws + 25600000);       //  1,600,000 B
    float* er        = (float*)(ws + 27200000);       //  1,600,000 B
    int*   counts    = (int*)  (ws + 28800000);       //    400,000 B
    int*   offsets   = (int*)  (ws + 29200000);       //    400,000 B
    int*   cursor    = (int*)  (ws + 29600000);       //    400,000 B
    int*   blockSums = (int*)  (ws + 30000000);       //        256 B
    unsigned long long* sedge = (unsigned long long*)(ws + 30400000); // 25,600,000 B
                                                      // total 56 MB

    hipMemsetAsync(counts, 0, (size_t)N_NODES * sizeof(int), stream);

    node_proj<<<1250, 256, 0, stream>>>(node_feat, Wfc, attn_l, attn_r, feat, el, er);
    hist<<<(N_EDGES + 255) / 256, 256, 0, stream>>>(dst, counts);
    scan1<<<SCAN_BLOCKS, 256, 0, stream>>>(counts, offsets, blockSums);
    scan2<<<1, 64, 0, stream>>>(blockSums, SCAN_BLOCKS);
    scan3<<<(N_NODES + 255) / 256, 256, 0, stream>>>(offsets, cursor, blockSums);
    scatter<<<(N_EDGES + 255) / 256, 256, 0, stream>>>(src, dst, cursor, sedge);
    aggregate<<<(N_NODES * 64 + 255) / 256, 256, 0, stream>>>(
        edge_feat, We, el, er, offsets, counts, sedge, feat, rst);
}